// Round 1
// baseline (755.141 us; speedup 1.0000x reference)
//
#include <hip/hip_runtime.h>

#define B 16
#define H 32
#define KVH 8
#define HD 128
#define S 4096
#define D 4096
#define NQKV 6144   // 4096 q + 1024 k + 1024 v columns
#define KSPLIT 8

// ---------------------------------------------------------------- KV copy
__global__ void k_copy(const float4* __restrict__ s1, float4* __restrict__ d1,
                       const float4* __restrict__ s2, float4* __restrict__ d2) {
  const long n = (long)B * KVH * S * HD / 4;  // 16,777,216 float4 per tensor
  const long stride = (long)gridDim.x * blockDim.x;
  for (long i = (long)blockIdx.x * blockDim.x + threadIdx.x; i < 2 * n; i += stride) {
    if (i < n) d1[i] = s1[i];
    else       d2[i - n] = s2[i - n];
  }
}

// ------------------------------------------------- QKV projection (M=16 GEMM)
// grid (NQKV/256, KSPLIT), block 256. Each thread: one output column n over a
// K-slice, 16 batch accumulators. Weight reads coalesced; hs reads wave-uniform.
__global__ void k_proj(const float* __restrict__ hs, const float* __restrict__ Wq,
                       const float* __restrict__ Wk, const float* __restrict__ Wv,
                       float* __restrict__ part) {
  int n = blockIdx.x * 256 + threadIdx.x;
  int k0 = blockIdx.y * (D / KSPLIT);
  const float* w; int ldw, col;
  if (n < 4096)      { w = Wq; ldw = 4096; col = n; }
  else if (n < 5120) { w = Wk; ldw = 1024; col = n - 4096; }
  else               { w = Wv; ldw = 1024; col = n - 5120; }
  float acc[B];
#pragma unroll
  for (int b = 0; b < B; b++) acc[b] = 0.f;
  const float* wp = w + (size_t)k0 * ldw + col;
#pragma unroll 4
  for (int k = 0; k < D / KSPLIT; k++) {
    float wv = wp[(size_t)k * ldw];
#pragma unroll
    for (int b = 0; b < B; b++) acc[b] = fmaf(hs[b * D + k0 + k], wv, acc[b]);
  }
  float* p = part + (size_t)blockIdx.y * (B * NQKV);
#pragma unroll
  for (int b = 0; b < B; b++) p[(size_t)b * NQKV + n] = acc[b];
}

__global__ void k_reduce_qkv(const float* __restrict__ part, float* __restrict__ qkv) {
  int i = blockIdx.x * 256 + threadIdx.x;  // < B*NQKV
  float s = 0.f;
#pragma unroll
  for (int c = 0; c < KSPLIT; c++) s += part[(size_t)c * B * NQKV + i];
  qkv[i] = s;
}

// ------------------------------------------- RoPE on q,k + scatter k,v to cache
__global__ void k_rope_scatter(const float* __restrict__ qkv, const float* __restrict__ cosb,
                               const float* __restrict__ sinb, const int* __restrict__ steps,
                               float* __restrict__ qr, float* __restrict__ newk,
                               float* __restrict__ newv) {
  int i = blockIdx.x * 256 + threadIdx.x;  // < B*NQKV
  int b = i / NQKV, n = i % NQKV;
  float val = qkv[(size_t)b * NQKV + n];
  if (n < 4096) {
    int d = n & 127;
    int pn = (d < 64) ? n + 64 : n - 64;
    float pv = qkv[(size_t)b * NQKV + pn];
    float rot = (d < 64) ? -pv : pv;
    qr[(size_t)b * D + n] = val * cosb[b * HD + d] + rot * sinb[b * HD + d];
  } else if (n < 5120) {
    int j = n - 4096, kvh = j >> 7, d = j & 127;
    int pn = (d < 64) ? n + 64 : n - 64;
    float pv = qkv[(size_t)b * NQKV + pn];
    float rot = (d < 64) ? -pv : pv;
    int st = steps[b];
    newk[((size_t)(b * KVH + kvh) * S + st) * HD + d] =
        val * cosb[b * HD + d] + rot * sinb[b * HD + d];
  } else {
    int j = n - 5120, kvh = j >> 7, d = j & 127;
    newv[((size_t)(b * KVH + kvh) * S + steps[b]) * HD + d] = val;
  }
}

// ----------------------------------------------- scores + softmax per (b,h)
// 512 blocks; mapping keeps the 4 heads sharing one KV panel on the same XCD
// (same blockIdx mod 8).
__global__ void k_scores(const float* __restrict__ qr, const float* __restrict__ newk,
                         const int* __restrict__ steps, float* __restrict__ probs,
                         float* __restrict__ invs) {
  int bid = blockIdx.x;
  int g = bid >> 7, j = bid & 127;
  int b = j >> 3, kvh = j & 7;
  int h = kvh * 4 + g;
  int t = threadIdx.x;
  __shared__ float qs[HD];
  __shared__ float red[4];
  if (t < HD / 4) ((float4*)qs)[t] = ((const float4*)(qr + (size_t)b * D + h * HD))[t];
  __syncthreads();
  int L = steps[b] + 1;
  const float* Kb = newk + (size_t)(b * KVH + kvh) * S * HD;
  float* pb = probs + (size_t)(b * H + h) * S;
  float lmax = -1e30f;
  for (int s = t; s < L; s += 256) {
    const float4* kr = (const float4*)(Kb + (size_t)s * HD);
    float acc = 0.f;
#pragma unroll
    for (int i = 0; i < HD / 4; i++) {
      float4 kk = kr[i];
      float4 qq = ((const float4*)qs)[i];
      acc = fmaf(kk.x, qq.x, fmaf(kk.y, qq.y, fmaf(kk.z, qq.z, fmaf(kk.w, qq.w, acc))));
    }
    float sc = acc * 0.08838834764831845f;  // 1/sqrt(128)
    pb[s] = sc;
    lmax = fmaxf(lmax, sc);
  }
#pragma unroll
  for (int o = 32; o > 0; o >>= 1) lmax = fmaxf(lmax, __shfl_xor(lmax, o));
  if ((t & 63) == 0) red[t >> 6] = lmax;
  __syncthreads();
  float gmax = fmaxf(fmaxf(red[0], red[1]), fmaxf(red[2], red[3]));
  float lsum = 0.f;
  for (int s = t; s < L; s += 256) {
    float p = __expf(pb[s] - gmax);
    pb[s] = p;
    lsum += p;
  }
#pragma unroll
  for (int o = 32; o > 0; o >>= 1) lsum += __shfl_xor(lsum, o);
  __syncthreads();
  if ((t & 63) == 0) red[t >> 6] = lsum;
  __syncthreads();
  if (t == 0) invs[b * H + h] = 1.f / (red[0] + red[1] + red[2] + red[3]);
}

// ----------------------------------------------- P·V with s-chunk split
// grid (KSPLIT, KVH, B), block 128: t -> (head-local 0..3, d-quad 0..31)
__global__ void k_pv(const float* __restrict__ probs, const float* __restrict__ newv,
                     const int* __restrict__ steps, float* __restrict__ outp) {
  int c = blockIdx.x, kvh = blockIdx.y, b = blockIdx.z;
  int t = threadIdx.x;
  int hl = t >> 5, dq = t & 31;
  int h = kvh * 4 + hl;
  int L = steps[b] + 1;
  int s0 = c * (S / KSPLIT);
  int s1 = min(s0 + S / KSPLIT, L);
  float4 acc = make_float4(0.f, 0.f, 0.f, 0.f);
  const float* pb = probs + (size_t)(b * H + h) * S;
  const float4* Vb = (const float4*)(newv + (size_t)(b * KVH + kvh) * S * HD) + dq;
#pragma unroll 4
  for (int s = s0; s < s1; s++) {
    float p = pb[s];
    float4 vv = Vb[(size_t)s * (HD / 4)];
    acc.x = fmaf(p, vv.x, acc.x);
    acc.y = fmaf(p, vv.y, acc.y);
    acc.z = fmaf(p, vv.z, acc.z);
    acc.w = fmaf(p, vv.w, acc.w);
  }
  float4* o = (float4*)(outp + ((size_t)(c * B + b) * KVH + kvh) * 512) + t;
  *o = acc;
}

__global__ void k_reduce_ctx(const float* __restrict__ outp, const float* __restrict__ invs,
                             float* __restrict__ ctx) {
  int i = blockIdx.x * 256 + threadIdx.x;  // < B*D
  int b = i >> 12, r = i & 4095, h = r >> 7, d = r & 127;
  int kvh = h >> 2, hl = h & 3;
  float s = 0.f;
#pragma unroll
  for (int c = 0; c < KSPLIT; c++)
    s += outp[((size_t)(c * B + b) * KVH + kvh) * 512 + hl * HD + d];
  ctx[i] = s * invs[b * H + h];
}

// ----------------------------------------------- output projection (M=16)
__global__ void k_wo(const float* __restrict__ ctx, const float* __restrict__ Wo,
                     float* __restrict__ part) {
  int n = blockIdx.x * 256 + threadIdx.x;  // < 4096
  int k0 = blockIdx.y * (D / KSPLIT);
  float acc[B];
#pragma unroll
  for (int b = 0; b < B; b++) acc[b] = 0.f;
  const float* wp = Wo + (size_t)k0 * D + n;
#pragma unroll 4
  for (int k = 0; k < D / KSPLIT; k++) {
    float wv = wp[(size_t)k * D];
#pragma unroll
    for (int b = 0; b < B; b++) acc[b] = fmaf(ctx[b * D + k0 + k], wv, acc[b]);
  }
  float* p = part + (size_t)blockIdx.y * (B * D);
#pragma unroll
  for (int b = 0; b < B; b++) p[(size_t)b * D + n] = acc[b];
}

__global__ void k_reduce_out(const float* __restrict__ part, float* __restrict__ out) {
  int i = blockIdx.x * 256 + threadIdx.x;  // < B*D
  float s = 0.f;
#pragma unroll
  for (int c = 0; c < KSPLIT; c++) s += part[(size_t)c * B * D + i];
  out[i] = s;
}

// ----------------------------------------------------------------- launch
extern "C" void kernel_launch(void* const* d_in, const int* in_sizes, int n_in,
                              void* d_out, int out_size, void* d_ws, size_t ws_size,
                              hipStream_t stream) {
  const float* hs    = (const float*)d_in[0];
  // d_in[1] attention_mask: unused (mask == truncation at current_step)
  const int*   steps = (const int*)d_in[2];
  const float* cosb  = (const float*)d_in[3];
  const float* sinb  = (const float*)d_in[4];
  const float* pk    = (const float*)d_in[5];
  const float* pvv   = (const float*)d_in[6];
  const float* Wq    = (const float*)d_in[7];
  const float* Wk    = (const float*)d_in[8];
  const float* Wv    = (const float*)d_in[9];
  const float* Wo    = (const float*)d_in[10];

  float* attn_out = (float*)d_out;
  float* newk = attn_out + (size_t)B * D;
  float* newv = newk + (size_t)B * KVH * S * HD;

  float* ws = (float*)d_ws;
  float* p_qkvpart = ws;                                  // 8*16*6144   = 786432
  float* p_qkv     = p_qkvpart + (size_t)KSPLIT * B * NQKV;  // 16*6144  =  98304
  float* p_qr      = p_qkv + (size_t)B * NQKV;               // 16*4096  =  65536
  float* p_probs   = p_qr + (size_t)B * D;                   // 512*4096 = 2097152
  float* p_invs    = p_probs + (size_t)B * H * S;            // 512
  float* p_outp    = p_invs + 512;                           // 8*16*8*512 = 524288
  float* p_ctx     = p_outp + (size_t)KSPLIT * B * KVH * 512;// 16*4096  =  65536
  float* p_wopart  = p_qkvpart;  // reuse (done after k_reduce_qkv)

  hipLaunchKernelGGL(k_copy, dim3(2048), dim3(256), 0, stream,
                     (const float4*)pk, (float4*)newk, (const float4*)pvv, (float4*)newv);
  hipLaunchKernelGGL(k_proj, dim3(NQKV / 256, KSPLIT), dim3(256), 0, stream,
                     hs, Wq, Wk, Wv, p_qkvpart);
  hipLaunchKernelGGL(k_reduce_qkv, dim3(B * NQKV / 256), dim3(256), 0, stream,
                     p_qkvpart, p_qkv);
  hipLaunchKernelGGL(k_rope_scatter, dim3(B * NQKV / 256), dim3(256), 0, stream,
                     p_qkv, cosb, sinb, steps, p_qr, newk, newv);
  hipLaunchKernelGGL(k_scores, dim3(B * H), dim3(256), 0, stream,
                     p_qr, newk, steps, p_probs, p_invs);
  hipLaunchKernelGGL(k_pv, dim3(KSPLIT, KVH, B), dim3(128), 0, stream,
                     p_probs, newv, steps, p_outp);
  hipLaunchKernelGGL(k_reduce_ctx, dim3(B * D / 256), dim3(256), 0, stream,
                     p_outp, p_invs, p_ctx);
  hipLaunchKernelGGL(k_wo, dim3(D / 256, KSPLIT), dim3(256), 0, stream,
                     p_ctx, Wo, p_wopart);
  hipLaunchKernelGGL(k_reduce_out, dim3(B * D / 256), dim3(256), 0, stream,
                     p_wopart, attn_out);
}

// Round 2
// 494.278 us; speedup vs baseline: 1.5278x; 1.5278x over previous
//
#include <hip/hip_runtime.h>

#define B 16
#define H 32
#define KVH 8
#define HD 128
#define S 4096
#define D 4096
#define NQKV 6144   // 4096 q + 1024 k + 1024 v columns
#define PSPLIT 8    // k-split for QKV projection
#define WSPLIT 8    // k-split for Wo projection
#define NCH 16      // chunks per (b,kvh) panel in fused copy kernels
#define CROWS (S / NCH)  // 256 rows per chunk
#define KSTRIDE 132      // LDS row stride (floats), 16B-aligned, 4-way max
#define VSTRIDE 130      // LDS row stride (floats), 8B-aligned

// ------------------------------------------------- QKV projection (M=16 GEMM)
__global__ void k_proj(const float* __restrict__ hs, const float* __restrict__ Wq,
                       const float* __restrict__ Wk, const float* __restrict__ Wv,
                       float* __restrict__ part) {
  int n = blockIdx.x * 256 + threadIdx.x;
  int k0 = blockIdx.y * (D / PSPLIT);
  const float* w; int ldw, col;
  if (n < 4096)      { w = Wq; ldw = 4096; col = n; }
  else if (n < 5120) { w = Wk; ldw = 1024; col = n - 4096; }
  else               { w = Wv; ldw = 1024; col = n - 5120; }
  float acc[B];
#pragma unroll
  for (int b = 0; b < B; b++) acc[b] = 0.f;
  const float* wp = w + (size_t)k0 * ldw + col;
#pragma unroll 4
  for (int k = 0; k < D / PSPLIT; k++) {
    float wv = wp[(size_t)k * ldw];
#pragma unroll
    for (int b = 0; b < B; b++) acc[b] = fmaf(hs[b * D + k0 + k], wv, acc[b]);
  }
  float* p = part + (size_t)blockIdx.y * (B * NQKV);
#pragma unroll
  for (int b = 0; b < B; b++) p[(size_t)b * NQKV + n] = acc[b];
}

// -------------------------------- reduce partials + RoPE -> qr, new k/v rows
__global__ void k_reduce_rope(const float* __restrict__ part, const float* __restrict__ cosb,
                              const float* __restrict__ sinb, const int* __restrict__ steps,
                              float* __restrict__ qr, float* __restrict__ nkrow,
                              float* __restrict__ nvrow) {
  int i = blockIdx.x * 256 + threadIdx.x;  // < B*NQKV
  int b = i / NQKV, n = i % NQKV;
  float v = 0.f;
#pragma unroll
  for (int c = 0; c < PSPLIT; c++) v += part[(size_t)c * B * NQKV + (size_t)b * NQKV + n];
  if (n < 5120) {
    int d = n & 127;
    int pn = (d < 64) ? n + 64 : n - 64;
    float pv = 0.f;
#pragma unroll
    for (int c = 0; c < PSPLIT; c++) pv += part[(size_t)c * B * NQKV + (size_t)b * NQKV + pn];
    float rot = (d < 64) ? -pv : pv;
    float r = v * cosb[b * HD + d] + rot * sinb[b * HD + d];
    if (n < 4096) qr[(size_t)b * D + n] = r;
    else          nkrow[(size_t)b * KVH * HD + (n - 4096)] = r;
  } else {
    nvrow[(size_t)b * KVH * HD + (n - 5120)] = v;
  }
}

// -------------------- fused: copy past_key -> new_key (+row sub) + QK scores
__global__ void k_fusedK(const float* __restrict__ pastk, const float* __restrict__ nkrow,
                         const float* __restrict__ qr, const int* __restrict__ steps,
                         float* __restrict__ newk, float* __restrict__ probs) {
  int ch = blockIdx.x, kvh = blockIdx.y, b = blockIdx.z;
  int t = threadIdx.x;
  __shared__ float qs[4 * HD];
  __shared__ float ks[32 * KSTRIDE];
  int s0 = ch * CROWS;
  int step = steps[b];
  int L = step + 1;
  int h0 = kvh * 4;
  if (t < 128)
    ((float4*)qs)[t] = ((const float4*)(qr + ((size_t)b * H + h0) * HD))[t];
  const float4* src = (const float4*)(pastk + ((size_t)(b * KVH + kvh) * S + s0) * HD);
  float4*       dst = (float4*)(newk + ((size_t)(b * KVH + kvh) * S + s0) * HD);
  const float4* sub = (const float4*)(nkrow + (size_t)(b * KVH + kvh) * HD);
  __syncthreads();
  for (int tile = 0; tile < CROWS / 32; ++tile) {
    int rbase = s0 + tile * 32;
#pragma unroll
    for (int i = 0; i < 4; i++) {
      int f4 = i * 256 + t;        // 0..1023
      int row = f4 >> 5;
      int d4 = f4 & 31;
      float4 v = src[(size_t)tile * 1024 + f4];
      if (rbase + row == step) v = sub[d4];
      dst[(size_t)tile * 1024 + f4] = v;
      *(float4*)&ks[row * KSTRIDE + d4 * 4] = v;
    }
    __syncthreads();
    int nact = min(L - rbase, 32);
    if (t < 128) {
      int h = t >> 5, row = t & 31;
      if (row < nact) {
        const float* kr = &ks[row * KSTRIDE];
        const float* qq = &qs[h * HD];
        float acc = 0.f;
#pragma unroll
        for (int i = 0; i < 32; i++) {
          float4 kk = *(const float4*)&kr[i * 4];
          float4 q4 = *(const float4*)&qq[i * 4];
          acc = fmaf(kk.x, q4.x, fmaf(kk.y, q4.y, fmaf(kk.z, q4.z, fmaf(kk.w, q4.w, acc))));
        }
        probs[(size_t)(b * H + h0 + h) * S + rbase + row] = acc * 0.08838834764831845f;
      }
    }
    __syncthreads();
  }
}

// ----------------------------------------------- softmax over scores (per b,h)
__global__ void k_softmax(const int* __restrict__ steps, float* __restrict__ probs,
                          float* __restrict__ invs) {
  int bid = blockIdx.x;
  int b = bid >> 5, h = bid & 31;
  int t = threadIdx.x;
  __shared__ float red[4];
  int L = steps[b] + 1;
  float* pb = probs + (size_t)(b * H + h) * S;
  float lmax = -1e30f;
  for (int s = t; s < L; s += 256) lmax = fmaxf(lmax, pb[s]);
#pragma unroll
  for (int o = 32; o > 0; o >>= 1) lmax = fmaxf(lmax, __shfl_xor(lmax, o));
  if ((t & 63) == 0) red[t >> 6] = lmax;
  __syncthreads();
  float gmax = fmaxf(fmaxf(red[0], red[1]), fmaxf(red[2], red[3]));
  float lsum = 0.f;
  for (int s = t; s < L; s += 256) {
    float p = __expf(pb[s] - gmax);
    pb[s] = p;
    lsum += p;
  }
#pragma unroll
  for (int o = 32; o > 0; o >>= 1) lsum += __shfl_xor(lsum, o);
  __syncthreads();
  if ((t & 63) == 0) red[t >> 6] = lsum;
  __syncthreads();
  if (t == 0) invs[b * H + h] = 1.f / (red[0] + red[1] + red[2] + red[3]);
}

// --------------------- fused: copy past_value -> new_value (+row sub) + P·V
__global__ void k_fusedV(const float* __restrict__ pastv, const float* __restrict__ nvrow,
                         const float* __restrict__ probs, const int* __restrict__ steps,
                         float* __restrict__ newv, float* __restrict__ part) {
  int ch = blockIdx.x, kvh = blockIdx.y, b = blockIdx.z;
  int t = threadIdx.x;
  __shared__ float vs[32 * VSTRIDE];
  __shared__ float ps[4 * 32];
  int s0 = ch * CROWS;
  int step = steps[b];
  int L = step + 1;
  int h0 = kvh * 4;
  int h = t >> 6, dl = t & 63;
  float2 acc = make_float2(0.f, 0.f);
  const float4* src = (const float4*)(pastv + ((size_t)(b * KVH + kvh) * S + s0) * HD);
  float4*       dst = (float4*)(newv + ((size_t)(b * KVH + kvh) * S + s0) * HD);
  const float4* sub = (const float4*)(nvrow + (size_t)(b * KVH + kvh) * HD);
  for (int tile = 0; tile < CROWS / 32; ++tile) {
    int rbase = s0 + tile * 32;
#pragma unroll
    for (int i = 0; i < 4; i++) {
      int f4 = i * 256 + t;
      int row = f4 >> 5;
      int d4 = f4 & 31;
      float4 v = src[(size_t)tile * 1024 + f4];
      if (rbase + row == step) v = sub[d4];
      dst[(size_t)tile * 1024 + f4] = v;
      *(float4*)&vs[row * VSTRIDE + d4 * 4] = v;
    }
    if (t < 128) {
      int h2 = t >> 5, row = t & 31;
      ps[h2 * 32 + row] =
          (rbase + row < L) ? probs[(size_t)(b * H + h0 + h2) * S + rbase + row] : 0.f;
    }
    __syncthreads();
    int nact = min(L - rbase, 32);
#pragma unroll 8
    for (int s = 0; s < nact; s++) {
      float p = ps[h * 32 + s];
      float2 vv = *(const float2*)&vs[s * VSTRIDE + dl * 2];
      acc.x = fmaf(p, vv.x, acc.x);
      acc.y = fmaf(p, vv.y, acc.y);
    }
    __syncthreads();
  }
  float* o = part + (((size_t)ch * B + b) * KVH + kvh) * 512 + h * 128 + dl * 2;
  o[0] = acc.x;
  o[1] = acc.y;
}

__global__ void k_reduce_ctx(const float* __restrict__ part, const float* __restrict__ invs,
                             float* __restrict__ ctx) {
  int i = blockIdx.x * 256 + threadIdx.x;  // < B*D
  int b = i >> 12, r = i & 4095, h = r >> 7, d = r & 127;
  int kvh = h >> 2, hl = h & 3;
  float s = 0.f;
#pragma unroll
  for (int c = 0; c < NCH; c++)
    s += part[(((size_t)c * B + b) * KVH + kvh) * 512 + hl * 128 + d];
  ctx[i] = s * invs[b * H + h];
}

// ----------------------------------------------- output projection (M=16)
__global__ void k_wo(const float* __restrict__ ctx, const float* __restrict__ Wo,
                     float* __restrict__ part) {
  int n = blockIdx.x * 256 + threadIdx.x;  // < 4096
  int k0 = blockIdx.y * (D / WSPLIT);
  float acc[B];
#pragma unroll
  for (int b = 0; b < B; b++) acc[b] = 0.f;
  const float* wp = Wo + (size_t)k0 * D + n;
#pragma unroll 4
  for (int k = 0; k < D / WSPLIT; k++) {
    float wv = wp[(size_t)k * D];
#pragma unroll
    for (int b = 0; b < B; b++) acc[b] = fmaf(ctx[b * D + k0 + k], wv, acc[b]);
  }
  float* p = part + (size_t)blockIdx.y * (B * D);
#pragma unroll
  for (int b = 0; b < B; b++) p[(size_t)b * D + n] = acc[b];
}

__global__ void k_reduce_out(const float* __restrict__ part, float* __restrict__ out) {
  int i = blockIdx.x * 256 + threadIdx.x;  // < B*D
  float s = 0.f;
#pragma unroll
  for (int c = 0; c < WSPLIT; c++) s += part[(size_t)c * B * D + i];
  out[i] = s;
}

// ----------------------------------------------------------------- launch
extern "C" void kernel_launch(void* const* d_in, const int* in_sizes, int n_in,
                              void* d_out, int out_size, void* d_ws, size_t ws_size,
                              hipStream_t stream) {
  const float* hs    = (const float*)d_in[0];
  const int*   steps = (const int*)d_in[2];
  const float* cosb  = (const float*)d_in[3];
  const float* sinb  = (const float*)d_in[4];
  const float* pk    = (const float*)d_in[5];
  const float* pvv   = (const float*)d_in[6];
  const float* Wq    = (const float*)d_in[7];
  const float* Wk    = (const float*)d_in[8];
  const float* Wv    = (const float*)d_in[9];
  const float* Wo    = (const float*)d_in[10];

  float* attn_out = (float*)d_out;
  float* newk = attn_out + (size_t)B * D;
  float* newv = newk + (size_t)B * KVH * S * HD;

  float* ws = (float*)d_ws;
  // shared region (disjoint lifetimes): qkv partials / PV partials / Wo partials
  float* p_shared = ws;                                        // 1,048,576 floats
  float* p_qr     = p_shared + 1048576;                        //    65,536
  float* p_nkrow  = p_qr + (size_t)B * D;                      //    16,384
  float* p_nvrow  = p_nkrow + (size_t)B * KVH * HD;            //    16,384
  float* p_probs  = p_nvrow + (size_t)B * KVH * HD;            // 2,097,152
  float* p_invs   = p_probs + (size_t)B * H * S;               //       512
  float* p_ctx    = p_invs + 512;                              //    65,536

  hipLaunchKernelGGL(k_proj, dim3(NQKV / 256, PSPLIT), dim3(256), 0, stream,
                     hs, Wq, Wk, Wv, p_shared);
  hipLaunchKernelGGL(k_reduce_rope, dim3(B * NQKV / 256), dim3(256), 0, stream,
                     p_shared, cosb, sinb, steps, p_qr, p_nkrow, p_nvrow);
  hipLaunchKernelGGL(k_fusedK, dim3(NCH, KVH, B), dim3(256), 0, stream,
                     pk, p_nkrow, p_qr, steps, newk, p_probs);
  hipLaunchKernelGGL(k_softmax, dim3(B * H), dim3(256), 0, stream,
                     steps, p_probs, p_invs);
  hipLaunchKernelGGL(k_fusedV, dim3(NCH, KVH, B), dim3(256), 0, stream,
                     pvv, p_nvrow, p_probs, steps, newv, p_shared);
  hipLaunchKernelGGL(k_reduce_ctx, dim3(B * D / 256), dim3(256), 0, stream,
                     p_shared, p_invs, p_ctx);
  hipLaunchKernelGGL(k_wo, dim3(D / 256, WSPLIT), dim3(256), 0, stream,
                     p_ctx, Wo, p_shared);
  hipLaunchKernelGGL(k_reduce_out, dim3(B * D / 256), dim3(256), 0, stream,
                     p_shared, attn_out);
}